// Round 2
// baseline (1117.038 us; speedup 1.0000x reference)
//
#include <hip/hip_runtime.h>
#include <math.h>

// T=1000, B=256, F_IN=13 x3 -> 39 features, H=100, 3H=300 (gate order r,z,n), 20 classes
#define T_STEPS 1000
#define BATCH   256
#define FIN     13
#define XDIM    39
#define HDIM    100
#define G3      300
#define NCLS    20

#define NCONS   320     // 5 consumer waves: 2 rows x 50-col-half per thread
#define NPROD   192     // 3 producer waves: 2 rows x 39 cols per thread
#define NTHR    512     // 8 waves total -> 2 waves/SIMD balanced
#define HHALF   52      // padded half stride for h in LDS (16B-aligned float4 reads)

__device__ __forceinline__ float fast_sigmoid(float v) {
    return 1.f / (1.f + __expf(-v));
}
__device__ __forceinline__ float fast_tanh(float v) {
    const float c = fminf(fmaxf(v, -15.f), 15.f);
    const float e = __expf(2.f * c);
    return (e - 1.f) / (e + 1.f);
}

// Design notes:
//  - Broadcast ds_read_b128 fans out 1KB/instr regardless of sharing -> instr count
//    is the cost. 2 rows/thread => each broadcast feeds 8 FMAs; consumer waves need
//    13 bcasts (52 h-floats). Producers (x-part of the GEMV) run one step ahead in
//    separate waves, off the h-recurrence critical path.
//  - ONE barrier per step: phase B is recomputed redundantly per consumer wave
//    (bit-identical values), so next-step broadcast reads only need own-wave writes.
//  - All cross-wave LDS buffers double-buffered; phase B reads only
//    consumer-written buffers (gi folded/copied in phase A) -> no producer race.
//  - Producer & consumer weight arrays SHARE registers (wA/wB): peak weight VGPRs
//    104, total ~110 < 256 cap from __launch_bounds__(512,2) -> no remat/spill.
__launch_bounds__(NTHR, 2)
__global__ void gru_persistent(const float* __restrict__ mfcc0,
                               const float* __restrict__ mfcc1,
                               const float* __restrict__ mfcc2,
                               const float* __restrict__ len0,
                               const float* __restrict__ W_ih,
                               const float* __restrict__ W_hh,
                               const float* __restrict__ b_ih,
                               const float* __restrict__ b_hh,
                               const float* __restrict__ W_out,
                               const float* __restrict__ b_out,
                               float* __restrict__ out)
{
    const int b    = blockIdx.x;
    const int tid  = threadIdx.x;
    const int lane = tid & 63;

    __shared__ __align__(16) float Vh[2][2 * HHALF];  // [h(0:50)+pad2 | h(50:100)+pad2]
    __shared__ __align__(16) float xbuf[2][40];       // x 39 + zero pad (x(t+1), x(t+2))
    __shared__ float gib[2][G3];                      // gi = W_ih@x + b_ih (producer-written)
    __shared__ float P0[2][304];                      // col-half-0 partial (+b_hh, +gi for r/z)
    __shared__ float P1[2][304];                      // col-half-1 raw partial
    __shared__ float INb[2][HDIM];                    // i_n copies (consumer-written)
    __shared__ float feat[2 * HDIM];

    const bool isCons = (tid < NCONS);

    // ---- consumer geometry: rows (ga, ga+1), col half cc ----
    const int cc  = (tid < 160) ? 0 : 1;              // col half (consumer only)
    const int pr  = (isCons ? tid : 0) % 160;         // pair id 0..159, active <150
    const int prc = (pr < 150) ? pr : 149;
    const int ga  = 2 * prc;
    const int gbr = ga + 1;

    // ---- producer geometry: rows (gpa, gpa+1), all 39 x-cols ----
    const int q0  = isCons ? 0 : (tid - NCONS);       // 0..191, active <150
    const int gpa = 2 * ((q0 < 150) ? q0 : 149);

    // ---- SHARED weight registers: consumers use wA/wB[0..12], producers [0..9] ----
    float4 wA[13], wB[13];
    float  bA = 0.f, bB = 0.f;
    if (isCons) {
        const float* sA = W_hh + ga  * HDIM + cc * 50;
        const float* sB = W_hh + gbr * HDIM + cc * 50;
        #pragma unroll
        for (int i = 0; i < 12; ++i) {
            wA[i] = make_float4(sA[4*i], sA[4*i+1], sA[4*i+2], sA[4*i+3]);
            wB[i] = make_float4(sB[4*i], sB[4*i+1], sB[4*i+2], sB[4*i+3]);
        }
        wA[12] = make_float4(sA[48], sA[49], 0.f, 0.f);   // pads hit zeroed Vh[50/51]
        wB[12] = make_float4(sB[48], sB[49], 0.f, 0.f);
        if (cc == 0) { bA = b_hh[ga]; bB = b_hh[gbr]; }
    } else {
        const float* sA = W_ih + (gpa)     * XDIM;
        const float* sB = W_ih + (gpa + 1) * XDIM;
        #pragma unroll
        for (int i = 0; i < 9; ++i) {
            wA[i] = make_float4(sA[4*i], sA[4*i+1], sA[4*i+2], sA[4*i+3]);
            wB[i] = make_float4(sB[4*i], sB[4*i+1], sB[4*i+2], sB[4*i+3]);
        }
        wA[9] = make_float4(sA[36], sA[37], sA[38], 0.f);  // pad pairs with xbuf[39]=0
        wB[9] = make_float4(sB[36], sB[37], sB[38], 0.f);
        #pragma unroll
        for (int i = 10; i < 13; ++i) { wA[i] = make_float4(0,0,0,0); wB[i] = make_float4(0,0,0,0); }
        bA = b_ih[gpa]; bB = b_ih[gpa + 1];
    }

    // ---- producer x streaming source ----
    const float* xsrc = mfcc0;
    int xoff = b * FIN;
    if (!isCons && q0 < XDIM) {
        const int f = q0 % FIN;
        xsrc = (q0 < FIN) ? mfcc0 : (q0 < 2 * FIN ? mfcc1 : mfcc2);
        xoff = b * FIN + f;
    }

    // ---- prologue: h0=0, stage x(0)/x(1), compute gi_0 ----
    if (tid < 2 * HHALF) { Vh[0][tid] = 0.f; Vh[1][tid] = 0.f; }  // pads stay 0 forever
    if (tid < 40) {
        float v0 = 0.f, v1 = 0.f;
        if (tid < XDIM) {
            const int f = tid % FIN;
            const float* xs = (tid < FIN) ? mfcc0 : (tid < 2 * FIN ? mfcc1 : mfcc2);
            v0 = xs[b * FIN + f];
            v1 = xs[(size_t)BATCH * FIN + b * FIN + f];
        }
        xbuf[0][tid] = v0; xbuf[1][tid] = v1;
    }
    __syncthreads();
    if (!isCons && q0 < 150) {
        const float4* X4 = (const float4*)xbuf[0];
        float a0=0,a1=0,a2=0,a3=0, c0=0,c1=0,c2=0,c3=0;
        #pragma unroll
        for (int i = 0; i < 10; ++i) {
            const float4 vv = X4[i];
            a0=fmaf(wA[i].x,vv.x,a0); a1=fmaf(wA[i].y,vv.y,a1);
            a2=fmaf(wA[i].z,vv.z,a2); a3=fmaf(wA[i].w,vv.w,a3);
            c0=fmaf(wB[i].x,vv.x,c0); c1=fmaf(wB[i].y,vv.y,c1);
            c2=fmaf(wB[i].z,vv.z,c2); c3=fmaf(wB[i].w,vv.w,c3);
        }
        gib[0][gpa]     = bA + ((a0+a1)+(a2+a3));
        gib[0][gpa + 1] = bB + ((c0+c1)+(c2+c3));
    }
    __syncthreads();

    float s1 = 0.f, s2 = 0.f, m1 = -INFINITY, m2 = -INFINITY;

    for (int t = 0; t < T_STEPS; ++t) {
        const int cur = t & 1;
        const int nxt = cur ^ 1;

        if (isCons) {
            // -------- phase A: 13 broadcast float4 reads feed 2 rows (8 FMAs each) --------
            const float4* V4 = (const float4*)(Vh[cur] + cc * HHALF);
            float a0=0,a1=0,a2=0,a3=0, c0=0,c1=0,c2=0,c3=0;
            #pragma unroll
            for (int i = 0; i < 13; ++i) {
                const float4 vv = V4[i];
                a0=fmaf(wA[i].x,vv.x,a0); a1=fmaf(wA[i].y,vv.y,a1);
                a2=fmaf(wA[i].z,vv.z,a2); a3=fmaf(wA[i].w,vv.w,a3);
                c0=fmaf(wB[i].x,vv.x,c0); c1=fmaf(wB[i].y,vv.y,c1);
                c2=fmaf(wB[i].z,vv.z,c2); c3=fmaf(wB[i].w,vv.w,c3);
            }
            const float dA = (a0+a1)+(a2+a3);
            const float dB = (c0+c1)+(c2+c3);
            if (pr < 150) {
                if (cc == 0) {
                    float vA = dA + bA, vB = dB + bB;
                    const float gA_ = gib[cur][ga], gB_ = gib[cur][gbr];
                    if (ga < 200) { vA += gA_; vB += gB_; }            // r/z rows: fold gi
                    else { INb[cur][ga - 200] = gA_; INb[cur][gbr - 200] = gB_; } // n rows: i_n copy
                    P0[cur][ga] = vA; P0[cur][gbr] = vB;
                } else {
                    P1[cur][ga] = dA; P1[cur][gbr] = dB;
                }
            }
        } else {
            // -------- producers: prefetch x(t+2), compute gi(t+1) --------
            float xv = 0.f;
            const bool doX = (q0 < XDIM) && (t + 2 < T_STEPS);
            if (doX) xv = xsrc[(size_t)(t + 2) * (BATCH * FIN) + xoff];
            if ((t + 1 < T_STEPS) && q0 < 150) {
                const float4* X4 = (const float4*)xbuf[nxt];
                float a0=0,a1=0,a2=0,a3=0, c0=0,c1=0,c2=0,c3=0;
                #pragma unroll
                for (int i = 0; i < 10; ++i) {
                    const float4 vv = X4[i];
                    a0=fmaf(wA[i].x,vv.x,a0); a1=fmaf(wA[i].y,vv.y,a1);
                    a2=fmaf(wA[i].z,vv.z,a2); a3=fmaf(wA[i].w,vv.w,a3);
                    c0=fmaf(wB[i].x,vv.x,c0); c1=fmaf(wB[i].y,vv.y,c1);
                    c2=fmaf(wB[i].z,vv.z,c2); c3=fmaf(wB[i].w,vv.w,c3);
                }
                gib[nxt][gpa]     = bA + ((a0+a1)+(a2+a3));
                gib[nxt][gpa + 1] = bB + ((c0+c1)+(c2+c3));
            }
            if (doX) xbuf[cur][q0] = xv;
        }
        __syncthreads();

        // -------- phase B: redundant per consumer wave (lanes 0..49, 2 elems each) --------
        if (isCons && lane < 50) {
            const int j = lane;
            const int k = j + 50;
            const float r1  = fast_sigmoid(P0[cur][j]       + P1[cur][j]);
            const float z1  = fast_sigmoid(P0[cur][100 + j] + P1[cur][100 + j]);
            const float hn1 = P0[cur][200 + j] + P1[cur][200 + j];
            const float n1  = fast_tanh(fmaf(r1, hn1, INb[cur][j]));
            const float ho1 = Vh[cur][j];
            const float hv1 = fmaf(z1, ho1 - n1, n1);      // (1-z)*n + z*h

            const float r2  = fast_sigmoid(P0[cur][k]       + P1[cur][k]);
            const float z2  = fast_sigmoid(P0[cur][100 + k] + P1[cur][100 + k]);
            const float hn2 = P0[cur][200 + k] + P1[cur][200 + k];
            const float n2  = fast_tanh(fmaf(r2, hn2, INb[cur][k]));
            const float ho2 = Vh[cur][HHALF + j];
            const float hv2 = fmaf(z2, ho2 - n2, n2);

            Vh[nxt][j]         = hv1;
            Vh[nxt][HHALF + j] = hv2;
            s1 += hv1; m1 = fmaxf(m1, hv1);
            s2 += hv2; m2 = fmaxf(m2, hv2);
        }
    }

    // ---- pooling + output linear ----
    if (tid < 50) {     // consumer wave 0 lanes hold valid accumulators
        feat[tid]        = s1 / len0[b];
        feat[50 + tid]   = s2 / len0[b];
        feat[100 + tid]  = m1;
        feat[150 + tid]  = m2;
    }
    __syncthreads();

    if (tid < NCLS) {
        float acc = b_out[tid];
        #pragma unroll 4
        for (int k = 0; k < 2 * HDIM; ++k)
            acc = fmaf(W_out[tid * 2 * HDIM + k], feat[k], acc);
        out[b * NCLS + tid] = acc;
    }
}

extern "C" void kernel_launch(void* const* d_in, const int* in_sizes, int n_in,
                              void* d_out, int out_size, void* d_ws, size_t ws_size,
                              hipStream_t stream)
{
    const float* mfcc0 = (const float*)d_in[0];
    const float* mfcc1 = (const float*)d_in[1];
    const float* mfcc2 = (const float*)d_in[2];
    const float* len0  = (const float*)d_in[3];
    const float* W_ih  = (const float*)d_in[4];
    const float* W_hh  = (const float*)d_in[5];
    const float* b_ih  = (const float*)d_in[6];
    const float* b_hh  = (const float*)d_in[7];
    const float* W_out = (const float*)d_in[8];
    const float* b_out = (const float*)d_in[9];
    float* out = (float*)d_out;

    gru_persistent<<<BATCH, NTHR, 0, stream>>>(
        mfcc0, mfcc1, mfcc2, len0, W_ih, W_hh, b_ih, b_hh, W_out, b_out, out);
}

// Round 3
// 756.216 us; speedup vs baseline: 1.4771x; 1.4771x over previous
//
#include <hip/hip_runtime.h>
#include <math.h>

// T=1000, B=256, F_IN=13 x3 -> 39 features, H=100, gates r,z,n (3H=300), 20 classes
#define T_STEPS 1000
#define BATCH   256
#define FIN     13
#define XDIM    39
#define HDIM    100
#define NCLS    20

#define NCONS   448     // 7 consumer waves: quad per hidden unit, 4 col-parts/lane
#define NTHR    640     // + 3 producer waves (192 threads, 150 active)
#define HPAD    112     // h padded to 4*28 for uniform float4 reads
#define PCOLS   28      // columns per lane part

__device__ __forceinline__ float fast_sigmoid(float v) {
    return 1.f / (1.f + __expf(-v));
}
__device__ __forceinline__ float fast_tanh(float v) {
    const float c = fminf(fmaxf(v, -15.f), 15.f);
    const float e = __expf(2.f * c);
    return (e - 1.f) / (e + 1.f);
}
// quad_perm butterfly (VALU DPP; all 4 quad lanes active in consumer waves)
__device__ __forceinline__ float quad_xor1(float v) {
    return __int_as_float(__builtin_amdgcn_update_dpp(0, __float_as_int(v), 0xB1, 0xF, 0xF, true)); // [1,0,3,2]
}
__device__ __forceinline__ float quad_xor2(float v) {
    return __int_as_float(__builtin_amdgcn_update_dpp(0, __float_as_int(v), 0x4E, 0xF, 0xF, true)); // [2,3,0,1]
}

// R2 lesson: bound = per-wave critical-path work + LDS round trips + barrier, NOT
// LDS instruction count. This round: quad-per-unit mapping -> gate triple (r,z,n)
// reduces inside a quad via DPP (no LDS, no extra barrier); h kept in registers;
// ONE barrier/step with a pure-VALU tail after it. Producers run gi one step ahead.
__launch_bounds__(NTHR, 2)
__global__ void gru_persistent(const float* __restrict__ mfcc0,
                               const float* __restrict__ mfcc1,
                               const float* __restrict__ mfcc2,
                               const float* __restrict__ len0,
                               const float* __restrict__ W_ih,
                               const float* __restrict__ W_hh,
                               const float* __restrict__ b_ih,
                               const float* __restrict__ b_hh,
                               const float* __restrict__ W_out,
                               const float* __restrict__ b_out,
                               float* __restrict__ out)
{
    const int b   = blockIdx.x;
    const int tid = threadIdx.x;

    __shared__ __align__(16) float Vh[2][HPAD];       // h(t), pads [100..112) stay 0
    __shared__ __align__(16) float gib[2][4 * HDIM];  // gi transposed: [j][r,z,n,pad]
    __shared__ __align__(16) float xbuf[2][40];       // x staging (39 + zero pad)
    __shared__ float feat[2 * HDIM];

    const bool isCons = (tid < NCONS);

    // ---- consumer geometry: quad q = hidden unit j, lane part p ----
    const int q  = tid >> 2;                    // 0..111 (consumers), idle q>=100
    const int p  = tid & 3;                     // column part
    const int j  = (q < HDIM) ? q : (HDIM - 1); // clamped unit id

    // ---- producer geometry: rows (gA, gA+1) of the 300 gi rows ----
    const int q0 = isCons ? 0 : (tid - NCONS);  // 0..191, active <150
    const int gA = 2 * ((q0 < 150) ? q0 : 149);
    const int gB = gA + 1;

    // ---- SHARED weight registers: consumers w[0..20], producers w[0..19] ----
    float4 w[21];
    float  bh0 = 0.f, bh1 = 0.f, bh2 = 0.f;     // consumer: b_hh triple; producer: b_ih pair
    int    ofA = 0, ofB = 0;                    // producer gib write offsets
    if (isCons) {
        const int base = PCOLS * p;
        #pragma unroll
        for (int rr = 0; rr < 3; ++rr) {
            const float* src = W_hh + (rr * HDIM + j) * HDIM;
            #pragma unroll
            for (int i = 0; i < 7; ++i) {
                const int c = base + 4 * i;
                float4 t;
                t.x = (c + 0 < HDIM) ? src[c + 0] : 0.f;
                t.y = (c + 1 < HDIM) ? src[c + 1] : 0.f;
                t.z = (c + 2 < HDIM) ? src[c + 2] : 0.f;
                t.w = (c + 3 < HDIM) ? src[c + 3] : 0.f;
                w[rr * 7 + i] = t;
            }
        }
        bh0 = b_hh[j]; bh1 = b_hh[HDIM + j]; bh2 = b_hh[2 * HDIM + j];
    } else {
        const float* sA = W_ih + gA * XDIM;
        const float* sB = W_ih + gB * XDIM;
        #pragma unroll
        for (int i = 0; i < 9; ++i) {
            w[i]      = make_float4(sA[4*i], sA[4*i+1], sA[4*i+2], sA[4*i+3]);
            w[10 + i] = make_float4(sB[4*i], sB[4*i+1], sB[4*i+2], sB[4*i+3]);
        }
        w[9]  = make_float4(sA[36], sA[37], sA[38], 0.f);   // pairs with xbuf[39]=0
        w[19] = make_float4(sB[36], sB[37], sB[38], 0.f);
        w[20] = make_float4(0, 0, 0, 0);
        bh0 = b_ih[gA]; bh1 = b_ih[gB];
        ofA = (gA % HDIM) * 4 + gA / HDIM;
        ofB = (gB % HDIM) * 4 + gB / HDIM;
    }

    // ---- producer x streaming source ----
    const float* xsrc = mfcc0;
    int xoff = b * FIN;
    if (!isCons && q0 < XDIM) {
        const int f = q0 % FIN;
        xsrc = (q0 < FIN) ? mfcc0 : (q0 < 2 * FIN ? mfcc1 : mfcc2);
        xoff = b * FIN + f;
    }

    // ---- prologue: h0 = 0 (both buffers, pads included), stage x(0)/x(1), gi(0) ----
    if (tid < HPAD) { Vh[0][tid] = 0.f; Vh[1][tid] = 0.f; }
    if (tid < 40) {
        float v0 = 0.f, v1 = 0.f;
        if (tid < XDIM) {
            const int f = tid % FIN;
            const float* xs = (tid < FIN) ? mfcc0 : (tid < 2 * FIN ? mfcc1 : mfcc2);
            v0 = xs[b * FIN + f];
            v1 = xs[(size_t)BATCH * FIN + b * FIN + f];
        }
        xbuf[0][tid] = v0; xbuf[1][tid] = v1;
    }
    __syncthreads();
    if (!isCons && q0 < 150) {
        const float4* X4 = (const float4*)xbuf[0];
        float a0=0,a1=0,a2=0,a3=0, c0=0,c1=0,c2=0,c3=0;
        #pragma unroll
        for (int i = 0; i < 10; ++i) {
            const float4 vv = X4[i];
            a0=fmaf(w[i].x,vv.x,a0);      a1=fmaf(w[i].y,vv.y,a1);
            a2=fmaf(w[i].z,vv.z,a2);      a3=fmaf(w[i].w,vv.w,a3);
            c0=fmaf(w[10+i].x,vv.x,c0);   c1=fmaf(w[10+i].y,vv.y,c1);
            c2=fmaf(w[10+i].z,vv.z,c2);   c3=fmaf(w[10+i].w,vv.w,c3);
        }
        gib[0][ofA] = bh0 + ((a0+a1)+(a2+a3));
        gib[0][ofB] = bh1 + ((c0+c1)+(c2+c3));
    }
    __syncthreads();

    float hreg = 0.f;                 // h_j, kept in registers (all 4 quad lanes)
    float sum = 0.f, mx = -INFINITY;

    for (int t = 0; t < T_STEPS; ++t) {
        const int cur = t & 1;
        const int nxt = cur ^ 1;

        if (isCons) {
            // ---- GEMV part: 7 bcast float4 reads, 3 gate rows x 28 cols ----
            const float4* V4 = (const float4*)(Vh[cur] + p * PCOLS);
            float a0=0,a1=0,a2=0,a3=0, b0=0,b1=0,b2=0,b3=0, c0=0,c1=0,c2=0,c3=0;
            #pragma unroll
            for (int i = 0; i < 7; ++i) {
                const float4 vv = V4[i];
                a0=fmaf(w[i].x,vv.x,a0);      a1=fmaf(w[i].y,vv.y,a1);
                a2=fmaf(w[i].z,vv.z,a2);      a3=fmaf(w[i].w,vv.w,a3);
                b0=fmaf(w[7+i].x,vv.x,b0);    b1=fmaf(w[7+i].y,vv.y,b1);
                b2=fmaf(w[7+i].z,vv.z,b2);    b3=fmaf(w[7+i].w,vv.w,b3);
                c0=fmaf(w[14+i].x,vv.x,c0);   c1=fmaf(w[14+i].y,vv.y,c1);
                c2=fmaf(w[14+i].z,vv.z,c2);   c3=fmaf(w[14+i].w,vv.w,c3);
            }
            float s0 = (a0+a1)+(a2+a3);
            float s1 = (b0+b1)+(b2+b3);
            float s2 = (c0+c1)+(c2+c3);
            // ---- quad butterfly (DPP, VALU pipe): all 4 lanes get full sums ----
            s0 += quad_xor1(s0); s0 += quad_xor2(s0);
            s1 += quad_xor1(s1); s1 += quad_xor2(s1);
            s2 += quad_xor1(s2); s2 += quad_xor2(s2);
            // ---- gates + state update, fully in-register ----
            const float4 g4 = *(const float4*)&gib[cur][j << 2];   // (i_r, i_z, i_n, -)
            const float rg = fast_sigmoid(g4.x + s0 + bh0);
            const float zg = fast_sigmoid(g4.y + s1 + bh1);
            const float ng = fast_tanh(fmaf(rg, s2 + bh2, g4.z));
            const float hv = fmaf(zg, hreg - ng, ng);              // (1-z)*n + z*h
            hreg = hv;
            sum += hv; mx = fmaxf(mx, hv);
            if (p == 0 && q < HDIM) Vh[nxt][q] = hv;               // publish h(t+1)
        } else {
            // ---- producers: prefetch x(t+2), compute gi(t+1) into gib[nxt] ----
            float xv = 0.f;
            const bool doX = (q0 < XDIM) && (t + 2 < T_STEPS);
            if (doX) xv = xsrc[(size_t)(t + 2) * (BATCH * FIN) + xoff];
            if ((t + 1 < T_STEPS) && q0 < 150) {
                const float4* X4 = (const float4*)xbuf[nxt];
                float a0=0,a1=0,a2=0,a3=0, c0=0,c1=0,c2=0,c3=0;
                #pragma unroll
                for (int i = 0; i < 10; ++i) {
                    const float4 vv = X4[i];
                    a0=fmaf(w[i].x,vv.x,a0);      a1=fmaf(w[i].y,vv.y,a1);
                    a2=fmaf(w[i].z,vv.z,a2);      a3=fmaf(w[i].w,vv.w,a3);
                    c0=fmaf(w[10+i].x,vv.x,c0);   c1=fmaf(w[10+i].y,vv.y,c1);
                    c2=fmaf(w[10+i].z,vv.z,c2);   c3=fmaf(w[10+i].w,vv.w,c3);
                }
                gib[nxt][ofA] = bh0 + ((a0+a1)+(a2+a3));
                gib[nxt][ofB] = bh1 + ((c0+c1)+(c2+c3));
            }
            if (doX) xbuf[cur][q0] = xv;
        }
        __syncthreads();
    }

    // ---- pooling + output linear ----
    if (isCons && p == 0 && q < HDIM) {
        feat[q]        = sum / len0[b];
        feat[HDIM + q] = mx;
    }
    __syncthreads();

    if (tid < NCLS) {
        float acc = b_out[tid];
        #pragma unroll 4
        for (int k = 0; k < 2 * HDIM; ++k)
            acc = fmaf(W_out[tid * 2 * HDIM + k], feat[k], acc);
        out[b * NCLS + tid] = acc;
    }
}

extern "C" void kernel_launch(void* const* d_in, const int* in_sizes, int n_in,
                              void* d_out, int out_size, void* d_ws, size_t ws_size,
                              hipStream_t stream)
{
    const float* mfcc0 = (const float*)d_in[0];
    const float* mfcc1 = (const float*)d_in[1];
    const float* mfcc2 = (const float*)d_in[2];
    const float* len0  = (const float*)d_in[3];
    const float* W_ih  = (const float*)d_in[4];
    const float* W_hh  = (const float*)d_in[5];
    const float* b_ih  = (const float*)d_in[6];
    const float* b_hh  = (const float*)d_in[7];
    const float* W_out = (const float*)d_in[8];
    const float* b_out = (const float*)d_in[9];
    float* out = (float*)d_out;

    gru_persistent<<<BATCH, NTHR, 0, stream>>>(
        mfcc0, mfcc1, mfcc2, len0, W_ih, W_hh, b_ih, b_hh, W_out, b_out, out);
}